// Round 3
// baseline (21.889 us; speedup 1.0000x reference)
//
#include <hip/hip_runtime.h>

// MorphTEmbedding: one wave per 2 tokens, each lane computes 8 consecutive
// embedding elements per token. e = lane*8+j  =>  a=lane>>3, b=lane&7, c=j.
// Direct global gathers (W is 2.56 MB, L2-resident) — no LDS, no barriers.
// Single-pass LayerNorm: var = E[v^2] - mu^2 (eps=1e-5 >> var ~1e-13, safe).

#define RANK      8
#define NUM_MORPH 10000
#define EMB       512
#define LN_EPS    1e-5f
#define STRIDE_R  (NUM_MORPH * 8)   // 80000 floats between ranks
#define WPB       4                 // waves per block (256 threads)
#define TPW       2                 // tokens per wave

__global__ __launch_bounds__(256) void morph_emb_kernel(
    const int* __restrict__ x,       // [n_tok]
    const int* __restrict__ co,      // [NUM_SURF, 3]
    const float* __restrict__ W,     // [RANK, NUM_MORPH, 8]
    const float* __restrict__ lns,   // [512]
    const float* __restrict__ lnb,   // [512]
    float* __restrict__ out,         // [n_tok, 512]
    int n_tok) {
    const int lane = threadIdx.x & 63;
    const int wid  = blockIdx.x * WPB + (threadIdx.x >> 6);
    const int t0   = wid * TPW;
    if (t0 >= n_tok) return;
    const bool has1 = (t0 + 1) < n_tok;

    // token surface ids (wave-uniform addresses -> single fetch each)
    const int s0 = x[t0];
    const int s1 = has1 ? x[t0 + 1] : s0;

    const int m00 = co[s0 * 3],     m01 = co[s0 * 3 + 1], m02 = co[s0 * 3 + 2];
    const int m10 = co[s1 * 3],     m11 = co[s1 * 3 + 1], m12 = co[s1 * 3 + 2];

    const int ia = lane >> 3;
    const int ib = lane & 7;

    const float* pa0 = W + m00 * 8 + ia;
    const float* pb0 = W + m01 * 8 + ib;
    const float* pc0 = W + m02 * 8;
    const float* pa1 = W + m10 * 8 + ia;
    const float* pb1 = W + m11 * 8 + ib;
    const float* pc1 = W + m12 * 8;

    float acc0[8] = {0,0,0,0,0,0,0,0};
    float acc1[8] = {0,0,0,0,0,0,0,0};

#pragma unroll
    for (int r = 0; r < RANK; ++r) {
        const int ro = r * STRIDE_R;
        const float  p0  = pa0[ro] * pb0[ro];
        const float4 q00 = *reinterpret_cast<const float4*>(pc0 + ro);
        const float4 q01 = *reinterpret_cast<const float4*>(pc0 + ro + 4);
        const float  p1  = pa1[ro] * pb1[ro];
        const float4 q10 = *reinterpret_cast<const float4*>(pc1 + ro);
        const float4 q11 = *reinterpret_cast<const float4*>(pc1 + ro + 4);
        acc0[0] += p0 * q00.x; acc0[1] += p0 * q00.y;
        acc0[2] += p0 * q00.z; acc0[3] += p0 * q00.w;
        acc0[4] += p0 * q01.x; acc0[5] += p0 * q01.y;
        acc0[6] += p0 * q01.z; acc0[7] += p0 * q01.w;
        acc1[0] += p1 * q10.x; acc1[1] += p1 * q10.y;
        acc1[2] += p1 * q10.z; acc1[3] += p1 * q10.w;
        acc1[4] += p1 * q11.x; acc1[5] += p1 * q11.y;
        acc1[6] += p1 * q11.z; acc1[7] += p1 * q11.w;
    }

    // ---- single-pass LayerNorm stats, both tokens interleaved ----
    float sA = 0.f, qA = 0.f, sB = 0.f, qB = 0.f;
#pragma unroll
    for (int j = 0; j < 8; ++j) {
        sA += acc0[j]; qA += acc0[j] * acc0[j];
        sB += acc1[j]; qB += acc1[j] * acc1[j];
    }
#pragma unroll
    for (int off = 32; off > 0; off >>= 1) {
        sA += __shfl_xor(sA, off); qA += __shfl_xor(qA, off);
        sB += __shfl_xor(sB, off); qB += __shfl_xor(qB, off);
    }
    const float muA = sA * (1.0f / EMB);
    const float muB = sB * (1.0f / EMB);
    const float rsA = rsqrtf(qA * (1.0f / EMB) - muA * muA + LN_EPS);
    const float rsB = rsqrtf(qB * (1.0f / EMB) - muB * muB + LN_EPS);

    const int e = lane << 3;
    const float4 g0 = *reinterpret_cast<const float4*>(&lns[e]);
    const float4 g1 = *reinterpret_cast<const float4*>(&lns[e + 4]);
    const float4 b0 = *reinterpret_cast<const float4*>(&lnb[e]);
    const float4 b1 = *reinterpret_cast<const float4*>(&lnb[e + 4]);
    const float gv[8] = {g0.x, g0.y, g0.z, g0.w, g1.x, g1.y, g1.z, g1.w};
    const float bv[8] = {b0.x, b0.y, b0.z, b0.w, b1.x, b1.y, b1.z, b1.w};

    float4 oA0, oA1;
    oA0.x = (acc0[0] - muA) * rsA * gv[0] + bv[0];
    oA0.y = (acc0[1] - muA) * rsA * gv[1] + bv[1];
    oA0.z = (acc0[2] - muA) * rsA * gv[2] + bv[2];
    oA0.w = (acc0[3] - muA) * rsA * gv[3] + bv[3];
    oA1.x = (acc0[4] - muA) * rsA * gv[4] + bv[4];
    oA1.y = (acc0[5] - muA) * rsA * gv[5] + bv[5];
    oA1.z = (acc0[6] - muA) * rsA * gv[6] + bv[6];
    oA1.w = (acc0[7] - muA) * rsA * gv[7] + bv[7];
    float* opA = out + (size_t)t0 * EMB + e;
    *reinterpret_cast<float4*>(opA)     = oA0;
    *reinterpret_cast<float4*>(opA + 4) = oA1;

    if (has1) {
        float4 oB0, oB1;
        oB0.x = (acc1[0] - muB) * rsB * gv[0] + bv[0];
        oB0.y = (acc1[1] - muB) * rsB * gv[1] + bv[1];
        oB0.z = (acc1[2] - muB) * rsB * gv[2] + bv[2];
        oB0.w = (acc1[3] - muB) * rsB * gv[3] + bv[3];
        oB1.x = (acc1[4] - muB) * rsB * gv[4] + bv[4];
        oB1.y = (acc1[5] - muB) * rsB * gv[5] + bv[5];
        oB1.z = (acc1[6] - muB) * rsB * gv[6] + bv[6];
        oB1.w = (acc1[7] - muB) * rsB * gv[7] + bv[7];
        float* opB = out + (size_t)(t0 + 1) * EMB + e;
        *reinterpret_cast<float4*>(opB)     = oB0;
        *reinterpret_cast<float4*>(opB + 4) = oB1;
    }
}

extern "C" void kernel_launch(void* const* d_in, const int* in_sizes, int n_in,
                              void* d_out, int out_size, void* d_ws, size_t ws_size,
                              hipStream_t stream) {
    const int*   x   = (const int*)d_in[0];
    const int*   co  = (const int*)d_in[1];
    const float* W   = (const float*)d_in[2];
    const float* lns = (const float*)d_in[3];
    const float* lnb = (const float*)d_in[4];
    float*       out = (float*)d_out;

    const int n_tok  = in_sizes[0];                       // 16384
    const int tok_per_block = WPB * TPW;                  // 8
    const int blocks = (n_tok + tok_per_block - 1) / tok_per_block;  // 2048
    morph_emb_kernel<<<blocks, WPB * 64, 0, stream>>>(x, co, W, lns, lnb, out, n_tok);
}

// Round 4
// 18.201 us; speedup vs baseline: 1.2026x; 1.2026x over previous
//
#include <hip/hip_runtime.h>

// MorphTEmbedding: 4 waves/block, 4 tokens/wave. Per wave: one coalesced
// gather phase (x -> co -> W, chain paid once for 4 tokens) stages
// 4 x 24 rows of 8 floats into LDS; then a global-load-free compute phase:
// e = lane*8+j => a=lane>>3, b=lane&7, c=j.
// Single-pass LN: var = E[v^2]-mu^2 (var ~1e-13 << eps=1e-5, safe).

#define RANK      8
#define NUM_MORPH 10000
#define EMB       512
#define LN_EPS    1e-5f
#define WPB       4        // waves per block (256 threads)
#define TPW       4        // tokens per wave

__global__ __launch_bounds__(256) void morph_emb_kernel(
    const int* __restrict__ x,       // [n_tok]
    const int* __restrict__ co,      // [NUM_SURF, 3]
    const float* __restrict__ W,     // [RANK, NUM_MORPH, 8]
    const float* __restrict__ lns,   // [512]
    const float* __restrict__ lnb,   // [512]
    float* __restrict__ out,         // [n_tok, 512]
    int n_tok) {
    const int lane  = threadIdx.x & 63;
    const int wave  = threadIdx.x >> 6;
    const int tbase = (blockIdx.x * WPB + wave) * TPW;
    if (tbase >= n_tok) return;

    __shared__ float cbuf[WPB][TPW][3][RANK][8];   // 12 KB

    // lanes 0..3 fetch the 4 surface ids (parallel, then broadcast)
    int s_ld = 0;
    if (lane < TPW) {
        int tt = tbase + lane;
        if (tt >= n_tok) tt = n_tok - 1;
        s_ld = x[tt];
    }

    // ---- gather phase: 192 float4 per wave = 3 per lane ----
#pragma unroll
    for (int q = 0; q < 3; ++q) {
        const int f    = q * 64 + lane;        // 0..191
        const int t    = f / 48;               // token within wave
        const int ff   = f - t * 48;           // 0..47
        const int row  = ff >> 1;              // 0..23 = o*8 + r
        const int o    = row >> 3;
        const int r    = row & 7;
        const int half = (ff & 1) << 2;
        const int s_t  = __shfl(s_ld, t);      // broadcast surface id
        const int m    = co[s_t * 3 + o];      // 16-lane broadcast load
        const float4 v = *reinterpret_cast<const float4*>(
            &W[(size_t)(r * NUM_MORPH + m) * 8 + half]);
        *reinterpret_cast<float4*>(&cbuf[wave][t][o][r][half]) = v;
    }

    // ln params (token-invariant): load while gather is in flight
    const int e = lane << 3;
    const float4 g0 = *reinterpret_cast<const float4*>(&lns[e]);
    const float4 g1 = *reinterpret_cast<const float4*>(&lns[e + 4]);
    const float4 b0 = *reinterpret_cast<const float4*>(&lnb[e]);
    const float4 b1 = *reinterpret_cast<const float4*>(&lnb[e + 4]);
    const float gv[8] = {g0.x, g0.y, g0.z, g0.w, g1.x, g1.y, g1.z, g1.w};
    const float bv[8] = {b0.x, b0.y, b0.z, b0.w, b1.x, b1.y, b1.z, b1.w};

    __syncthreads();

    // ---- compute phase: all 4 tokens interleaved, LDS-only ----
    const int ia = lane >> 3;
    const int ib = lane & 7;

    float acc[TPW][8] = {};
#pragma unroll
    for (int r = 0; r < RANK; ++r) {
#pragma unroll
        for (int t = 0; t < TPW; ++t) {
            const float  p  = cbuf[wave][t][0][r][ia] * cbuf[wave][t][1][r][ib];
            const float4 q0 = *reinterpret_cast<const float4*>(&cbuf[wave][t][2][r][0]);
            const float4 q1 = *reinterpret_cast<const float4*>(&cbuf[wave][t][2][r][4]);
            acc[t][0] += p * q0.x; acc[t][1] += p * q0.y;
            acc[t][2] += p * q0.z; acc[t][3] += p * q0.w;
            acc[t][4] += p * q1.x; acc[t][5] += p * q1.y;
            acc[t][6] += p * q1.z; acc[t][7] += p * q1.w;
        }
    }

    // ---- LN stats: 8 independent shuffle chains ----
    float sm[TPW], sq[TPW];
#pragma unroll
    for (int t = 0; t < TPW; ++t) {
        float s = 0.f, q = 0.f;
#pragma unroll
        for (int j = 0; j < 8; ++j) { s += acc[t][j]; q += acc[t][j] * acc[t][j]; }
        sm[t] = s; sq[t] = q;
    }
#pragma unroll
    for (int off = 32; off > 0; off >>= 1) {
#pragma unroll
        for (int t = 0; t < TPW; ++t) {
            sm[t] += __shfl_xor(sm[t], off);
            sq[t] += __shfl_xor(sq[t], off);
        }
    }

    // ---- normalize + store ----
#pragma unroll
    for (int t = 0; t < TPW; ++t) {
        if (tbase + t < n_tok) {
            const float mu = sm[t] * (1.0f / EMB);
            const float rs = rsqrtf(sq[t] * (1.0f / EMB) - mu * mu + LN_EPS);
            float4 o0, o1;
            o0.x = (acc[t][0] - mu) * rs * gv[0] + bv[0];
            o0.y = (acc[t][1] - mu) * rs * gv[1] + bv[1];
            o0.z = (acc[t][2] - mu) * rs * gv[2] + bv[2];
            o0.w = (acc[t][3] - mu) * rs * gv[3] + bv[3];
            o1.x = (acc[t][4] - mu) * rs * gv[4] + bv[4];
            o1.y = (acc[t][5] - mu) * rs * gv[5] + bv[5];
            o1.z = (acc[t][6] - mu) * rs * gv[6] + bv[6];
            o1.w = (acc[t][7] - mu) * rs * gv[7] + bv[7];
            float* op = out + (size_t)(tbase + t) * EMB + e;
            *reinterpret_cast<float4*>(op)     = o0;
            *reinterpret_cast<float4*>(op + 4) = o1;
        }
    }
}

extern "C" void kernel_launch(void* const* d_in, const int* in_sizes, int n_in,
                              void* d_out, int out_size, void* d_ws, size_t ws_size,
                              hipStream_t stream) {
    const int*   x   = (const int*)d_in[0];
    const int*   co  = (const int*)d_in[1];
    const float* W   = (const float*)d_in[2];
    const float* lns = (const float*)d_in[3];
    const float* lnb = (const float*)d_in[4];
    float*       out = (float*)d_out;

    const int n_tok = in_sizes[0];                          // 16384
    const int tok_per_block = WPB * TPW;                    // 16
    const int blocks = (n_tok + tok_per_block - 1) / tok_per_block;  // 1024
    morph_emb_kernel<<<blocks, WPB * 64, 0, stream>>>(x, co, W, lns, lnb, out, n_tok);
}

// Round 6
// 16.518 us; speedup vs baseline: 1.3251x; 1.1019x over previous
//
#include <hip/hip_runtime.h>

// MorphTEmbedding R6: one wave per token, zero-DS design (no LDS, no shuffles).
// Lane layout: element e = j*64 + lane (j=0..7). Then
//   a = e>>6 = j         (varies per element -> wave-uniform A row, via readlane/SGPR)
//   b = (e>>3)&7 = lane>>3  (per-lane scalar, one VMEM broadcast load per rank)
//   c = e&7   = lane&7      (per-lane scalar, one VMEM broadcast load per rank)
// acc[j] = sum_r (B_r*C_r) * A[r][j];  A[r][j] distributed by ONE load
// (lane r*8+d holds W[r,m0,d]) and consumed via v_readlane -> SGPR FMA operand.
// LayerNorm: DPP row-16 butterfly + 4 readlanes (no DS pipe at all).
// var = E[v^2]-mu^2 (var ~1e-12 << eps=1e-5; matched reference in R2-R4).

#define RANK      8
#define NUM_MORPH 10000
#define EMB       512
#define LN_EPS    1e-5f
#define WPB       4                 // waves per block (256 threads)
#define RSTRIDE   80000             // floats between ranks in W

__device__ __forceinline__ float dpp_add_b1(float v) {
    return v + __int_as_float(__builtin_amdgcn_update_dpp(
        __float_as_int(v), __float_as_int(v), 0xB1, 0xf, 0xf, false));
}
__device__ __forceinline__ float dpp_add_4e(float v) {
    return v + __int_as_float(__builtin_amdgcn_update_dpp(
        __float_as_int(v), __float_as_int(v), 0x4E, 0xf, 0xf, false));
}
__device__ __forceinline__ float dpp_add_hm(float v) {
    return v + __int_as_float(__builtin_amdgcn_update_dpp(
        __float_as_int(v), __float_as_int(v), 0x141, 0xf, 0xf, false));
}
__device__ __forceinline__ float dpp_add_m(float v) {
    return v + __int_as_float(__builtin_amdgcn_update_dpp(
        __float_as_int(v), __float_as_int(v), 0x140, 0xf, 0xf, false));
}
__device__ __forceinline__ float rdlane(float v, int l) {
    return __int_as_float(__builtin_amdgcn_readlane(__float_as_int(v), l));
}

__global__ __launch_bounds__(256) void morph_emb_kernel(
    const int* __restrict__ x,       // [n_tok]
    const int* __restrict__ co,      // [NUM_SURF, 3]
    const float* __restrict__ W,     // [RANK, NUM_MORPH, 8]
    const float* __restrict__ lns,   // [512]
    const float* __restrict__ lnb,   // [512]
    float* __restrict__ out,         // [n_tok, 512]
    int n_tok) {
    const int lane = threadIdx.x & 63;
    const int wid  = blockIdx.x * WPB + (threadIdx.x >> 6);
    const int tok  = (wid < n_tok) ? wid : (n_tok - 1);   // no divergence: clamp

    // LN params (token-invariant, issued first): g[j]=lns[j*64+lane]
    float gv[8], bv[8];
#pragma unroll
    for (int j = 0; j < 8; ++j) {
        gv[j] = lns[j * 64 + lane];
        bv[j] = lnb[j * 64 + lane];
    }

    // token chain (wave-uniform values, plain loads)
    const int s  = x[tok];
    const int m0 = co[s * 3 + 0];
    const int m1 = co[s * 3 + 1];
    const int m2 = co[s * 3 + 2];

    // A distribution: lane (r=lane>>3, d=lane&7) holds W[r, m0, d] — ONE load
    const float a_mine =
        W[(size_t)(lane >> 3) * RSTRIDE + (size_t)m0 * 8 + (lane & 7)];

    // B,C per-lane scalars (broadcast loads, 32B footprint each)
    const float* pb = W + (size_t)m1 * 8 + (lane >> 3);
    const float* pc = W + (size_t)m2 * 8 + (lane & 7);
    float p[RANK];
#pragma unroll
    for (int r = 0; r < RANK; ++r)
        p[r] = pb[r * RSTRIDE] * pc[r * RSTRIDE];

    // acc[j] = sum_r p[r] * A[r][j]; A via readlane -> SGPR operand of v_fmac
    float acc[8] = {0.f, 0.f, 0.f, 0.f, 0.f, 0.f, 0.f, 0.f};
#pragma unroll
    for (int r = 0; r < RANK; ++r) {
#pragma unroll
        for (int j = 0; j < 8; ++j)
            acc[j] = fmaf(p[r], rdlane(a_mine, r * 8 + j), acc[j]);
    }

    // ---- LayerNorm stats: DPP row-16 reduce + 4 readlanes (zero DS) ----
    float sm = 0.f, sq = 0.f;
#pragma unroll
    for (int j = 0; j < 8; ++j) { sm += acc[j]; sq += acc[j] * acc[j]; }
    sm = dpp_add_b1(sm); sq = dpp_add_b1(sq);
    sm = dpp_add_4e(sm); sq = dpp_add_4e(sq);
    sm = dpp_add_hm(sm); sq = dpp_add_hm(sq);
    sm = dpp_add_m(sm);  sq = dpp_add_m(sq);
    const float tot_s = (rdlane(sm, 0) + rdlane(sm, 16)) +
                        (rdlane(sm, 32) + rdlane(sm, 48));
    const float tot_q = (rdlane(sq, 0) + rdlane(sq, 16)) +
                        (rdlane(sq, 32) + rdlane(sq, 48));
    const float mu = tot_s * (1.0f / EMB);
    const float rs = rsqrtf(tot_q * (1.0f / EMB) - mu * mu + LN_EPS);

    // ---- normalize + store: 8 fully-coalesced 256B dword stores ----
    if (wid < n_tok) {
        float* op = out + (size_t)wid * EMB + lane;
#pragma unroll
        for (int j = 0; j < 8; ++j)
            op[j * 64] = (acc[j] - mu) * rs * gv[j] + bv[j];
    }
}

extern "C" void kernel_launch(void* const* d_in, const int* in_sizes, int n_in,
                              void* d_out, int out_size, void* d_ws, size_t ws_size,
                              hipStream_t stream) {
    const int*   x   = (const int*)d_in[0];
    const int*   co  = (const int*)d_in[1];
    const float* W   = (const float*)d_in[2];
    const float* lns = (const float*)d_in[3];
    const float* lnb = (const float*)d_in[4];
    float*       out = (float*)d_out;

    const int n_tok  = in_sizes[0];                 // 16384
    const int blocks = (n_tok + WPB - 1) / WPB;     // 4096
    morph_emb_kernel<<<blocks, WPB * 64, 0, stream>>>(x, co, W, lns, lnb, out, n_tok);
}